// Round 5
// baseline (218.769 us; speedup 1.0000x reference)
//
#include <hip/hip_runtime.h>

typedef __bf16 bf16x8 __attribute__((ext_vector_type(8)));
typedef float f32x4 __attribute__((ext_vector_type(4)));
typedef unsigned short u16;
typedef unsigned int u32;
typedef u16 u16x4 __attribute__((ext_vector_type(4)));
typedef u16 u16x8 __attribute__((ext_vector_type(8)));

#define L2ALPHA (-0.014499569f)   // log2(0.99)

static __device__ __forceinline__ u16 f2bf(float f) {
    u32 u = __builtin_bit_cast(u32, f);
    return (u16)((u + 0x7FFFu + ((u >> 16) & 1u)) >> 16);
}

// async global->LDS, 16B per lane, dest must be wave-uniform-base + lane*16
static __device__ __forceinline__ void gl2lds16(const void* g, void* l) {
    __builtin_amdgcn_global_load_lds(
        (const __attribute__((address_space(1))) u32*)g,
        (__attribute__((address_space(3))) u32*)l, 16, 0, 0);
}

// ---------------------------------------------------------------------------
// prep: x (fp32, 8.39M) -> xbf (bf16 row-major); W (fp32 [256][768]) -> wbf
// (bf16 fragment-order, 6 panels x 32768 u16). Both live in d_out scratch.
// grid 4288 x 256: blocks [0,4096) = xconv, [4096,4288) = wconv.
// ---------------------------------------------------------------------------
__global__ void prep_kernel(const float* __restrict__ x, const float* __restrict__ Wq,
                            u16* __restrict__ xbf, u16* __restrict__ wbf) {
    if (blockIdx.x < 4096) {
        size_t f = ((size_t)blockIdx.x * 256 + threadIdx.x) * 8;
        const float4 a = *(const float4*)(x + f);
        const float4 c = *(const float4*)(x + f + 4);
        u16x8 h;
        h[0] = f2bf(a.x); h[1] = f2bf(a.y); h[2] = f2bf(a.z); h[3] = f2bf(a.w);
        h[4] = f2bf(c.x); h[5] = f2bf(c.y); h[6] = f2bf(c.z); h[7] = f2bf(c.w);
        *(u16x8*)(xbf + f) = h;
    } else {
        int idx = (blockIdx.x - 4096) * 256 + threadIdx.x;   // 0..49151
        int flat = idx * 4;
        int k = flat / 768;
        int n = flat - k * 768;
        const float4 v4 = *(const float4*)(Wq + flat);
        float vv[4] = {v4.x, v4.y, v4.z, v4.w};
        #pragma unroll
        for (int e = 0; e < 4; ++e) {
            int col = n + e;
            int nb = col >> 7, c = col & 127;
            wbf[((nb * 32 + (k >> 3)) * 128 + c) * 8 + (k & 7)] = f2bf(vv[e]);
        }
    }
}

// ---------------------------------------------------------------------------
// Projection v3: zero-LDS, zero-barrier. A/B fragments read directly as b128
// global loads from xbf/wbf (L1/L2-hot). grid 1536 = 6 nb x 256 m-tiles,
// block 256 (4 waves, 64x64 quadrants of a 128x128 tile).
// ---------------------------------------------------------------------------
__global__ __launch_bounds__(256, 3) void proj_kernel(
        const u16* __restrict__ xbf, const u16* __restrict__ wbf,
        const float* __restrict__ bias,
        u16* __restrict__ qb, u16* __restrict__ kb, u16* __restrict__ vb)
{
    const int tid = threadIdx.x, lane = tid & 63, w = tid >> 6;
    const int l = blockIdx.x;
    const int nb = l % 6;
    const int mt = l / 6;                 // 0..255
    const int m0 = mt * 128, n0 = nb * 128;
    const int wr = (w & 1) * 64, wc = (w >> 1) * 64;
    const int m = lane & 15, quad = lane >> 4;

    const u16* wp = wbf + nb * 32768;

    f32x4 acc[4][4];
    #pragma unroll
    for (int rt = 0; rt < 4; ++rt)
        #pragma unroll
        for (int ct = 0; ct < 4; ++ct)
            acc[rt][ct] = f32x4{0.f, 0.f, 0.f, 0.f};

    #pragma unroll
    for (int kt = 0; kt < 8; ++kt) {
        bf16x8 af[4], bfr[4];
        #pragma unroll
        for (int rt = 0; rt < 4; ++rt)
            af[rt] = *(const bf16x8*)(xbf + (size_t)(m0 + wr + rt * 16 + m) * 256 + kt * 32 + quad * 8);
        #pragma unroll
        for (int ct = 0; ct < 4; ++ct)
            bfr[ct] = *(const bf16x8*)(wp + ((kt * 4 + quad) * 128 + wc + ct * 16 + m) * 8);
        #pragma unroll
        for (int rt = 0; rt < 4; ++rt)
            #pragma unroll
            for (int ct = 0; ct < 4; ++ct)
                acc[rt][ct] = __builtin_amdgcn_mfma_f32_16x16x32_bf16(
                    af[rt], bfr[ct], acc[rt][ct], 0, 0, 0);
    }

    const int b = m0 >> 12;
    const int jbase = (m0 & 4095) + wr;
    const int d0 = (nb & 1) * 128;

    if (nb < 2) {
        // Q: [row][d] bf16, pre-scaled by 1/sqrt(256)
        #pragma unroll
        for (int rt = 0; rt < 4; ++rt)
            #pragma unroll
            for (int ct = 0; ct < 4; ++ct) {
                int coll = wc + ct * 16 + m;
                float bv = bias[d0 + coll];
                #pragma unroll
                for (int r = 0; r < 4; ++r) {
                    int row = m0 + wr + rt * 16 + quad * 4 + r;
                    qb[(size_t)row * 256 + d0 + coll] = f2bf((acc[rt][ct][r] + bv) * 0.0625f);
                }
            }
    } else if (nb < 4) {
        // K fragment-order: [b][jt][h][k8][qk*16+mk][e], e=d&7
        #pragma unroll
        for (int rt = 0; rt < 4; ++rt)
            #pragma unroll
            for (int ct = 0; ct < 4; ++ct) {
                int d = d0 + wc + ct * 16 + m;
                float bv = bias[256 + d];
                int k8 = d >> 5, qk = (d >> 3) & 3, e = d & 7;
                #pragma unroll
                for (int r = 0; r < 4; ++r) {
                    int j = jbase + rt * 16 + quad * 4 + r;
                    int jt = j >> 5, hh = (j >> 4) & 1, mk = j & 15;
                    kb[((((size_t)(b * 128 + jt) * 2 + hh) * 8 + k8) * 64 + qk * 16 + mk) * 8 + e]
                        = f2bf(acc[rt][ct][r] + bv);
                }
            }
    } else {
        // V fragment-order: [b][jt][dt][qv*16+mv][e], e=j&7 -> u16x4 over r
        #pragma unroll
        for (int rt = 0; rt < 4; ++rt)
            #pragma unroll
            for (int ct = 0; ct < 4; ++ct) {
                int d = d0 + wc + ct * 16 + m;
                float bv = bias[512 + d];
                int dt = d >> 4, mv = d & 15;
                int j = jbase + rt * 16 + quad * 4;
                int jt = j >> 5, qv = (j >> 3) & 3, e0 = j & 7;
                u16x4 hv;
                #pragma unroll
                for (int r = 0; r < 4; ++r) hv[r] = f2bf(acc[rt][ct][r] + bv);
                *(u16x4*)&vb[(((size_t)(b * 128 + jt) * 16 + dt) * 64 + qv * 16 + mv) * 8 + e0] = hv;
            }
    }
}

// ---------------------------------------------------------------------------
// Windowed flash-retention v3: BM=256, 8 waves x 32 q-rows -> each K/V b-frag
// feeds 2 MFMAs (0.53 b128/MFMA). grid 128 (16 m-tiles x 8 batches), 1 blk/CU.
// Double-buffered fragment-order K/V panels via global_load_lds.
// ---------------------------------------------------------------------------
__global__ __launch_bounds__(512, 2) void attn_kernel(
        const u16* __restrict__ qb, const u16* __restrict__ kb,
        const u16* __restrict__ vb, float* __restrict__ out)
{
    __shared__ __align__(16) u16 Kf[2][8192];      // 2 x 16 KB
    __shared__ __align__(16) u16 Vf[2][8192];      // 2 x 16 KB
    __shared__ __align__(16) u16 Ps[8 * 32 * 40];  // per-wave P (32 rows), stride 40

    const int tid = threadIdx.x, lane = tid & 63, w = tid >> 6;   // w 0..7
    const int l = blockIdx.x;
    const int b = l & 7;                  // XCD-affine batch
    const int m0 = (l >> 3) * 256;
    const int qrow0 = m0 + w * 32;
    const int m = lane & 15, quad = lane >> 4;
    const size_t rowbase = (size_t)b * 4096;

    // q fragments: 2 row-groups x full D=256 (A-layout), direct from global
    bf16x8 qf[2][8];
    #pragma unroll
    for (int rg = 0; rg < 2; ++rg)
        #pragma unroll
        for (int k8 = 0; k8 < 8; ++k8)
            qf[rg][k8] = *(const bf16x8*)(qb + (rowbase + qrow0 + rg * 16 + m) * 256 + k8 * 32 + quad * 8);

    f32x4 acc[2][16];
    #pragma unroll
    for (int rg = 0; rg < 2; ++rg)
        #pragma unroll
        for (int dt = 0; dt < 16; ++dt)
            acc[rg][dt] = f32x4{0.f, 0.f, 0.f, 0.f};

    int t0 = (m0 - 1024) >> 5; if (t0 < 0) t0 = 0;
    const int t1 = (m0 >> 5) + 7;

    // prefetch first panel into buffer 0 (512 threads -> 2 lines each)
    {
        const u16* kp = kb + (size_t)(b * 128 + t0) * 8192;
        const u16* vp = vb + (size_t)(b * 128 + t0) * 8192;
        #pragma unroll
        for (int s = 0; s < 2; ++s) {
            int c = tid + 512 * s;
            gl2lds16(kp + (size_t)c * 8, &Kf[0][c * 8]);
            gl2lds16(vp + (size_t)c * 8, &Vf[0][c * 8]);
        }
    }

    int p = 0;
    for (int t = t0; t <= t1; ++t) {
        __syncthreads();   // drains async copy of buf p; all waves done with buf p^1
        if (t < t1) {
            const u16* kp = kb + (size_t)(b * 128 + t + 1) * 8192;
            const u16* vp = vb + (size_t)(b * 128 + t + 1) * 8192;
            #pragma unroll
            for (int s = 0; s < 2; ++s) {
                int c = tid + 512 * s;
                gl2lds16(kp + (size_t)c * 8, &Kf[p ^ 1][c * 8]);
                gl2lds16(vp + (size_t)c * 8, &Vf[p ^ 1][c * 8]);
            }
        }
        const int j0 = t * 32;

        // wave-uniform skip: tile all-future for this wave's 32 rows, or
        // entirely beyond the decay window
        if (j0 <= qrow0 + 31 && j0 + 1055 >= qrow0) {
            // S = q.k^T : two 16-key halves x two row-groups, b-frag reused x2
            f32x4 sA0{0.f,0.f,0.f,0.f}, sA1{0.f,0.f,0.f,0.f};
            f32x4 sB0{0.f,0.f,0.f,0.f}, sB1{0.f,0.f,0.f,0.f};
            #pragma unroll
            for (int k8 = 0; k8 < 8; ++k8) {
                bf16x8 bf0 = *(const bf16x8*)&Kf[p][(k8 * 64 + lane) * 8];
                sA0 = __builtin_amdgcn_mfma_f32_16x16x32_bf16(qf[0][k8], bf0, sA0, 0, 0, 0);
                sA1 = __builtin_amdgcn_mfma_f32_16x16x32_bf16(qf[1][k8], bf0, sA1, 0, 0, 0);
            }
            #pragma unroll
            for (int k8 = 0; k8 < 8; ++k8) {
                bf16x8 bf1 = *(const bf16x8*)&Kf[p][((8 + k8) * 64 + lane) * 8];
                sB0 = __builtin_amdgcn_mfma_f32_16x16x32_bf16(qf[0][k8], bf1, sB0, 0, 0, 0);
                sB1 = __builtin_amdgcn_mfma_f32_16x16x32_bf16(qf[1][k8], bf1, sB1, 0, 0, 0);
            }

            // decay-mask, bf16-cast, C-layout -> A-layout via per-wave LDS
            #pragma unroll
            for (int rg = 0; rg < 2; ++rg) {
                f32x4 sh0 = rg ? sA1 : sA0;
                f32x4 sh1 = rg ? sB1 : sB0;
                #pragma unroll
                for (int r = 0; r < 4; ++r) {
                    int i = qrow0 + rg * 16 + quad * 4 + r;
                    int dd0 = i - (j0 + m);
                    int dd1 = dd0 - 16;
                    float w0 = (dd0 >= 0) ? __builtin_amdgcn_exp2f((float)dd0 * L2ALPHA) : 0.0f;
                    float w1 = (dd1 >= 0) ? __builtin_amdgcn_exp2f((float)dd1 * L2ALPHA) : 0.0f;
                    int rowb = (w * 32 + rg * 16 + quad * 4 + r) * 40;
                    Ps[rowb + m]      = f2bf(sh0[r] * w0);
                    Ps[rowb + 16 + m] = f2bf(sh1[r] * w1);
                }
            }
            asm volatile("s_waitcnt lgkmcnt(0)" ::: "memory");  // wave-local P visibility

            bf16x8 pa0 = *(const bf16x8*)&Ps[(w * 32 + m) * 40 + quad * 8];
            bf16x8 pa1 = *(const bf16x8*)&Ps[(w * 32 + 16 + m) * 40 + quad * 8];

            // O += P @ V : v-frag reused across both row-groups
            #pragma unroll
            for (int dt = 0; dt < 16; ++dt) {
                bf16x8 vf = *(const bf16x8*)&Vf[p][(dt * 64 + lane) * 8];
                acc[0][dt] = __builtin_amdgcn_mfma_f32_16x16x32_bf16(pa0, vf, acc[0][dt], 0, 0, 0);
                acc[1][dt] = __builtin_amdgcn_mfma_f32_16x16x32_bf16(pa1, vf, acc[1][dt], 0, 0, 0);
            }
        }
        p ^= 1;
    }

    #pragma unroll
    for (int rg = 0; rg < 2; ++rg)
        #pragma unroll
        for (int dt = 0; dt < 16; ++dt)
            #pragma unroll
            for (int r = 0; r < 4; ++r)
                out[(rowbase + qrow0 + rg * 16 + quad * 4 + r) * 256 + dt * 16 + m] = acc[rg][dt][r];
}

// ---------------------------------------------------------------------------
extern "C" void kernel_launch(void* const* d_in, const int* in_sizes, int n_in,
                              void* d_out, int out_size, void* d_ws, size_t ws_size,
                              hipStream_t stream) {
    (void)in_sizes; (void)n_in; (void)out_size; (void)ws_size;
    const float* x    = (const float*)d_in[0];
    const float* Wq   = (const float*)d_in[1];
    const float* bias = (const float*)d_in[2];
    float* outp = (float*)d_out;

    const size_t per = (size_t)8 * 4096 * 256;   // elems per q/k/v buffer (48 MB total)
    u16* qb = (u16*)d_ws;
    u16* kb = qb + per;
    u16* vb = kb + per;

    // d_out doubles as prep scratch (17.2 MB of 33.5); attn overwrites it all.
    u16* wbf = (u16*)d_out;                       // 196608 u16 = 384 KB
    u16* xbf = wbf + 196608;                      // 8.39M u16 = 16 MB

    prep_kernel<<<4288, 256, 0, stream>>>(x, Wq, xbf, wbf);
    proj_kernel<<<1536, 256, 0, stream>>>(xbf, wbf, bias, qb, kb, vb);
    attn_kernel<<<128, 512, 0, stream>>>(qb, kb, vb, outp);
}

// Round 7
// 197.040 us; speedup vs baseline: 1.1103x; 1.1103x over previous
//
#include <hip/hip_runtime.h>

typedef __bf16 bf16x8 __attribute__((ext_vector_type(8)));
typedef float f32x4 __attribute__((ext_vector_type(4)));
typedef unsigned short u16;
typedef unsigned int u32;
typedef u16 u16x4 __attribute__((ext_vector_type(4)));
typedef u16 u16x8 __attribute__((ext_vector_type(8)));

#define L2ALPHA (-0.014499569f)   // log2(0.99)

static __device__ __forceinline__ u16 f2bf(float f) {
    u32 u = __builtin_bit_cast(u32, f);
    return (u16)((u + 0x7FFFu + ((u >> 16) & 1u)) >> 16);
}

// async global->LDS, 16B per lane, dest must be wave-uniform-base + lane*16
static __device__ __forceinline__ void gl2lds16(const void* g, void* l) {
    __builtin_amdgcn_global_load_lds(
        (const __attribute__((address_space(1))) u32*)g,
        (__attribute__((address_space(3))) u32*)l, 16, 0, 0);
}

// ---------------------------------------------------------------------------
// Projection v4: one barrier total. W panel staged cooperatively once; x
// staged wave-private (32 rows/wave) each kt -> no __syncthreads in k-loop,
// 1-deep register prefetch of next kt's x. grid 1536 = 6 nb x 256 mt,
// block 256 (4 waves; wave w owns rows w*32..w*32+31, all 128 cols).
// ---------------------------------------------------------------------------
__global__ __launch_bounds__(256, 2) void proj_kernel(
        const float* __restrict__ x, const float* __restrict__ Wq,
        const float* __restrict__ bias,
        u16* __restrict__ qb, u16* __restrict__ kb, u16* __restrict__ vb)
{
    __shared__ __align__(16) u16 Bs[32 * 128 * 8];   // 64 KB: [k8][col][e]
    __shared__ __align__(16) u16 As[4][32 * 40];     // 10 KB, wave-private, stride 40

    const int tid = threadIdx.x, lane = tid & 63, w = tid >> 6;
    const int l = blockIdx.x;
    const int nb = l % 6;
    const int mt = l / 6;                 // 0..255
    const int m0 = mt * 128, n0 = nb * 128;
    const int m = lane & 15, quad = lane >> 4;

    // ---- stage W panel (256 x 128 fp32 -> bf16 fragment order), once ----
    {
        const int col = tid & 127;
        const int khalf = tid >> 7;
        #pragma unroll
        for (int s = 0; s < 32; ++s) {
            int k0 = (khalf + 2 * s) * 4;
            u16x4 h;
            #pragma unroll
            for (int i = 0; i < 4; ++i)
                h[i] = f2bf(Wq[(k0 + i) * 768 + n0 + col]);
            *(u16x4*)&Bs[((k0 >> 3) * 128 + col) * 8 + (k0 & 7)] = h;
        }
    }
    __syncthreads();   // the only block-wide barrier

    // wave-private x staging coords: lane -> row r (0..31), k-half h (0..1)
    const int r = lane & 31, h = lane >> 5;
    const float* xrow = x + (size_t)(m0 + w * 32 + r) * 256 + h * 16;
    u16* As_w = &As[w][0];

    f32x4 acc[2][8];
    #pragma unroll
    for (int rt = 0; rt < 2; ++rt)
        #pragma unroll
        for (int ct = 0; ct < 8; ++ct)
            acc[rt][ct] = f32x4{0.f, 0.f, 0.f, 0.f};

    float4 g0 = *(const float4*)(xrow + 0);
    float4 g1 = *(const float4*)(xrow + 4);
    float4 g2 = *(const float4*)(xrow + 8);
    float4 g3 = *(const float4*)(xrow + 12);

    for (int kt = 0; kt < 8; ++kt) {
        // convert + wave-private LDS write
        u16x8 ha, hb;
        ha[0]=f2bf(g0.x); ha[1]=f2bf(g0.y); ha[2]=f2bf(g0.z); ha[3]=f2bf(g0.w);
        ha[4]=f2bf(g1.x); ha[5]=f2bf(g1.y); ha[6]=f2bf(g1.z); ha[7]=f2bf(g1.w);
        hb[0]=f2bf(g2.x); hb[1]=f2bf(g2.y); hb[2]=f2bf(g2.z); hb[3]=f2bf(g2.w);
        hb[4]=f2bf(g3.x); hb[5]=f2bf(g3.y); hb[6]=f2bf(g3.z); hb[7]=f2bf(g3.w);
        *(u16x8*)&As_w[r * 40 + h * 16]     = ha;
        *(u16x8*)&As_w[r * 40 + h * 16 + 8] = hb;

        // prefetch next kt's globals (independent of this kt's compute)
        if (kt < 7) {
            const float* xn = xrow + (kt + 1) * 32;
            g0 = *(const float4*)(xn + 0);
            g1 = *(const float4*)(xn + 4);
            g2 = *(const float4*)(xn + 8);
            g3 = *(const float4*)(xn + 12);
        }

        asm volatile("s_waitcnt lgkmcnt(0)" ::: "memory");  // wave-local As ready

        bf16x8 af[2], bfr[8];
        #pragma unroll
        for (int rt = 0; rt < 2; ++rt)
            af[rt] = *(const bf16x8*)&As_w[(rt * 16 + m) * 40 + quad * 8];
        #pragma unroll
        for (int ct = 0; ct < 8; ++ct)
            bfr[ct] = *(const bf16x8*)&Bs[((kt * 4 + quad) * 128 + ct * 16 + m) * 8];
        #pragma unroll
        for (int rt = 0; rt < 2; ++rt)
            #pragma unroll
            for (int ct = 0; ct < 8; ++ct)
                acc[rt][ct] = __builtin_amdgcn_mfma_f32_16x16x32_bf16(
                    af[rt], bfr[ct], acc[rt][ct], 0, 0, 0);
    }

    const int b = m0 >> 12;
    const int jbase = (m0 & 4095) + w * 32;
    const int d0 = (nb & 1) * 128;

    if (nb < 2) {
        // Q: [row][d] bf16, pre-scaled by 1/sqrt(256)
        #pragma unroll
        for (int rt = 0; rt < 2; ++rt)
            #pragma unroll
            for (int ct = 0; ct < 8; ++ct) {
                int coll = ct * 16 + m;
                float bv = bias[d0 + coll];
                #pragma unroll
                for (int rr = 0; rr < 4; ++rr) {
                    int row = m0 + w * 32 + rt * 16 + quad * 4 + rr;
                    qb[(size_t)row * 256 + d0 + coll] = f2bf((acc[rt][ct][rr] + bv) * 0.0625f);
                }
            }
    } else if (nb < 4) {
        // K fragment-order: [b][jt][h][k8][qk*16+mk][e], e=d&7
        #pragma unroll
        for (int rt = 0; rt < 2; ++rt)
            #pragma unroll
            for (int ct = 0; ct < 8; ++ct) {
                int d = d0 + ct * 16 + m;
                float bv = bias[256 + d];
                int k8 = d >> 5, qk = (d >> 3) & 3, e = d & 7;
                #pragma unroll
                for (int rr = 0; rr < 4; ++rr) {
                    int j = jbase + rt * 16 + quad * 4 + rr;
                    int jt = j >> 5, hh = (j >> 4) & 1, mk = j & 15;
                    kb[((((size_t)(b * 128 + jt) * 2 + hh) * 8 + k8) * 64 + qk * 16 + mk) * 8 + e]
                        = f2bf(acc[rt][ct][rr] + bv);
                }
            }
    } else {
        // V fragment-order: [b][jt][dt][qv*16+mv][e], e=j&7 -> u16x4 over rr
        #pragma unroll
        for (int rt = 0; rt < 2; ++rt)
            #pragma unroll
            for (int ct = 0; ct < 8; ++ct) {
                int d = d0 + ct * 16 + m;
                float bv = bias[512 + d];
                int dt = d >> 4, mv = d & 15;
                int j = jbase + rt * 16 + quad * 4;
                int jt = j >> 5, qv = (j >> 3) & 3, e0 = j & 7;
                u16x4 hv;
                #pragma unroll
                for (int rr = 0; rr < 4; ++rr) hv[rr] = f2bf(acc[rt][ct][rr] + bv);
                *(u16x4*)&vb[(((size_t)(b * 128 + jt) * 16 + dt) * 64 + qv * 16 + mv) * 8 + e0] = hv;
            }
    }
}

// ---------------------------------------------------------------------------
// Windowed flash-retention v4 (grid FIXED): BM=128, 4 waves x 32 q-rows
// (b-frag reuse x2 -> 0.53 b128/MFMA). grid 256 = 32 mt x 8 batches, 1 blk/CU.
// LDS pipe is the binding resource: 4 waves x ~34 reads x 12cyc/iter.
// ---------------------------------------------------------------------------
__global__ __launch_bounds__(256, 2) void attn_kernel(
        const u16* __restrict__ qb, const u16* __restrict__ kb,
        const u16* __restrict__ vb, float* __restrict__ out)
{
    __shared__ __align__(16) u16 Kf[2][8192];      // 2 x 16 KB
    __shared__ __align__(16) u16 Vf[2][8192];      // 2 x 16 KB
    __shared__ __align__(16) u16 Ps[4 * 32 * 40];  // per-wave P (32 rows), stride 40

    const int tid = threadIdx.x, lane = tid & 63, w = tid >> 6;   // w 0..3
    const int l = blockIdx.x;
    const int b = l & 7;                  // XCD-affine batch
    const int m0 = (l >> 3) * 128;        // l>>3 in [0,32)
    const int qrow0 = m0 + w * 32;
    const int m = lane & 15, quad = lane >> 4;
    const size_t rowbase = (size_t)b * 4096;

    // q fragments: 2 row-groups x full D=256 (A-layout), direct from global
    bf16x8 qf[2][8];
    #pragma unroll
    for (int rg = 0; rg < 2; ++rg)
        #pragma unroll
        for (int k8 = 0; k8 < 8; ++k8)
            qf[rg][k8] = *(const bf16x8*)(qb + (rowbase + qrow0 + rg * 16 + m) * 256 + k8 * 32 + quad * 8);

    f32x4 acc[2][16];
    #pragma unroll
    for (int rg = 0; rg < 2; ++rg)
        #pragma unroll
        for (int dt = 0; dt < 16; ++dt)
            acc[rg][dt] = f32x4{0.f, 0.f, 0.f, 0.f};

    int t0 = (m0 - 1024) >> 5; if (t0 < 0) t0 = 0;
    const int t1 = (m0 >> 5) + 3;         // <= 127

    // prefetch first panel into buffer 0 (256 threads -> 4 lines each)
    {
        const u16* kp = kb + (size_t)(b * 128 + t0) * 8192;
        const u16* vp = vb + (size_t)(b * 128 + t0) * 8192;
        #pragma unroll
        for (int s = 0; s < 4; ++s) {
            int c = tid + 256 * s;
            gl2lds16(kp + (size_t)c * 8, &Kf[0][c * 8]);
            gl2lds16(vp + (size_t)c * 8, &Vf[0][c * 8]);
        }
    }

    int p = 0;
    for (int t = t0; t <= t1; ++t) {
        __syncthreads();   // drains async copy of buf p; all waves done with buf p^1
        if (t < t1) {
            const u16* kp = kb + (size_t)(b * 128 + t + 1) * 8192;
            const u16* vp = vb + (size_t)(b * 128 + t + 1) * 8192;
            #pragma unroll
            for (int s = 0; s < 4; ++s) {
                int c = tid + 256 * s;
                gl2lds16(kp + (size_t)c * 8, &Kf[p ^ 1][c * 8]);
                gl2lds16(vp + (size_t)c * 8, &Vf[p ^ 1][c * 8]);
            }
        }
        const int j0 = t * 32;

        // wave-uniform skip: tile all-future for this wave's 32 rows, or
        // entirely beyond the decay window
        if (j0 <= qrow0 + 31 && j0 + 1055 >= qrow0) {
            // S = q.k^T : two 16-key halves x two row-groups, b-frag reused x2
            f32x4 sA0{0.f,0.f,0.f,0.f}, sA1{0.f,0.f,0.f,0.f};
            f32x4 sB0{0.f,0.f,0.f,0.f}, sB1{0.f,0.f,0.f,0.f};
            #pragma unroll
            for (int k8 = 0; k8 < 8; ++k8) {
                bf16x8 bf0 = *(const bf16x8*)&Kf[p][(k8 * 64 + lane) * 8];
                sA0 = __builtin_amdgcn_mfma_f32_16x16x32_bf16(qf[0][k8], bf0, sA0, 0, 0, 0);
                sA1 = __builtin_amdgcn_mfma_f32_16x16x32_bf16(qf[1][k8], bf0, sA1, 0, 0, 0);
            }
            #pragma unroll
            for (int k8 = 0; k8 < 8; ++k8) {
                bf16x8 bf1 = *(const bf16x8*)&Kf[p][((8 + k8) * 64 + lane) * 8];
                sB0 = __builtin_amdgcn_mfma_f32_16x16x32_bf16(qf[0][k8], bf1, sB0, 0, 0, 0);
                sB1 = __builtin_amdgcn_mfma_f32_16x16x32_bf16(qf[1][k8], bf1, sB1, 0, 0, 0);
            }

            // decay-mask, bf16-cast, C-layout -> A-layout via per-wave LDS
            #pragma unroll
            for (int rg = 0; rg < 2; ++rg) {
                f32x4 sh0 = rg ? sA1 : sA0;
                f32x4 sh1 = rg ? sB1 : sB0;
                #pragma unroll
                for (int rr = 0; rr < 4; ++rr) {
                    int i = qrow0 + rg * 16 + quad * 4 + rr;
                    int dd0 = i - (j0 + m);
                    int dd1 = dd0 - 16;
                    float w0 = (dd0 >= 0) ? __builtin_amdgcn_exp2f((float)dd0 * L2ALPHA) : 0.0f;
                    float w1 = (dd1 >= 0) ? __builtin_amdgcn_exp2f((float)dd1 * L2ALPHA) : 0.0f;
                    int rowb = (w * 32 + rg * 16 + quad * 4 + rr) * 40;
                    Ps[rowb + m]      = f2bf(sh0[rr] * w0);
                    Ps[rowb + 16 + m] = f2bf(sh1[rr] * w1);
                }
            }
            asm volatile("s_waitcnt lgkmcnt(0)" ::: "memory");  // wave-local P visibility

            bf16x8 pa0 = *(const bf16x8*)&Ps[(w * 32 + m) * 40 + quad * 8];
            bf16x8 pa1 = *(const bf16x8*)&Ps[(w * 32 + 16 + m) * 40 + quad * 8];

            // O += P @ V : v-frag reused across both row-groups
            #pragma unroll
            for (int dt = 0; dt < 16; ++dt) {
                bf16x8 vf = *(const bf16x8*)&Vf[p][(dt * 64 + lane) * 8];
                acc[0][dt] = __builtin_amdgcn_mfma_f32_16x16x32_bf16(pa0, vf, acc[0][dt], 0, 0, 0);
                acc[1][dt] = __builtin_amdgcn_mfma_f32_16x16x32_bf16(pa1, vf, acc[1][dt], 0, 0, 0);
            }
        }
        p ^= 1;
    }

    #pragma unroll
    for (int rg = 0; rg < 2; ++rg)
        #pragma unroll
        for (int dt = 0; dt < 16; ++dt)
            #pragma unroll
            for (int rr = 0; rr < 4; ++rr)
                out[(rowbase + qrow0 + rg * 16 + quad * 4 + rr) * 256 + dt * 16 + m] = acc[rg][dt][rr];
}

// ---------------------------------------------------------------------------
extern "C" void kernel_launch(void* const* d_in, const int* in_sizes, int n_in,
                              void* d_out, int out_size, void* d_ws, size_t ws_size,
                              hipStream_t stream) {
    (void)in_sizes; (void)n_in; (void)out_size; (void)ws_size;
    const float* x    = (const float*)d_in[0];
    const float* Wq   = (const float*)d_in[1];
    const float* bias = (const float*)d_in[2];
    float* outp = (float*)d_out;

    const size_t per = (size_t)8 * 4096 * 256;   // elems per q/k/v buffer (48 MB total)
    u16* qb = (u16*)d_ws;
    u16* kb = qb + per;
    u16* vb = kb + per;

    proj_kernel<<<1536, 256, 0, stream>>>(x, Wq, bias, qb, kb, vb);
    attn_kernel<<<256, 256, 0, stream>>>(qb, kb, vb, outp);
}

// Round 8
// 177.797 us; speedup vs baseline: 1.2304x; 1.1082x over previous
//
#include <hip/hip_runtime.h>

typedef __bf16 bf16x8 __attribute__((ext_vector_type(8)));
typedef float f32x4 __attribute__((ext_vector_type(4)));
typedef unsigned short u16;
typedef unsigned int u32;
typedef u16 u16x4 __attribute__((ext_vector_type(4)));
typedef u16 u16x8 __attribute__((ext_vector_type(8)));

#define L2ALPHA (-0.014499569f)   // log2(0.99)

static __device__ __forceinline__ u16 f2bf(float f) {
    u32 u = __builtin_bit_cast(u32, f);
    return (u16)((u + 0x7FFFu + ((u >> 16) & 1u)) >> 16);
}

// async global->LDS, 16B per lane, dest must be wave-uniform-base + lane*16
static __device__ __forceinline__ void gl2lds16(const void* g, void* l) {
    __builtin_amdgcn_global_load_lds(
        (const __attribute__((address_space(1))) u32*)g,
        (__attribute__((address_space(3))) u32*)l, 16, 0, 0);
}

// ---------------------------------------------------------------------------
// Projection v4 (unchanged structure): one barrier total; W panel staged once;
// x staged wave-private each kt. K panel now stored with EVEN/ODD key split:
// within a 32-key tile, B-frag half h = key&1, slot = key>>1 (lets attn pack
// the P-mask writes as u32).
// ---------------------------------------------------------------------------
__global__ __launch_bounds__(256, 2) void proj_kernel(
        const float* __restrict__ x, const float* __restrict__ Wq,
        const float* __restrict__ bias,
        u16* __restrict__ qb, u16* __restrict__ kb, u16* __restrict__ vb)
{
    __shared__ __align__(16) u16 Bs[32 * 128 * 8];   // 64 KB: [k8][col][e]
    __shared__ __align__(16) u16 As[4][32 * 40];     // 10 KB, wave-private

    const int tid = threadIdx.x, lane = tid & 63, w = tid >> 6;
    const int l = blockIdx.x;
    const int nb = l % 6;
    const int mt = l / 6;                 // 0..255
    const int m0 = mt * 128, n0 = nb * 128;
    const int m = lane & 15, quad = lane >> 4;

    // ---- stage W panel (256 x 128 fp32 -> bf16 fragment order), once ----
    {
        const int col = tid & 127;
        const int khalf = tid >> 7;
        #pragma unroll
        for (int s = 0; s < 32; ++s) {
            int k0 = (khalf + 2 * s) * 4;
            u16x4 h;
            #pragma unroll
            for (int i = 0; i < 4; ++i)
                h[i] = f2bf(Wq[(k0 + i) * 768 + n0 + col]);
            *(u16x4*)&Bs[((k0 >> 3) * 128 + col) * 8 + (k0 & 7)] = h;
        }
    }
    __syncthreads();   // the only block-wide barrier

    const int r = lane & 31, h = lane >> 5;
    const float* xrow = x + (size_t)(m0 + w * 32 + r) * 256 + h * 16;
    u16* As_w = &As[w][0];

    f32x4 acc[2][8];
    #pragma unroll
    for (int rt = 0; rt < 2; ++rt)
        #pragma unroll
        for (int ct = 0; ct < 8; ++ct)
            acc[rt][ct] = f32x4{0.f, 0.f, 0.f, 0.f};

    float4 g0 = *(const float4*)(xrow + 0);
    float4 g1 = *(const float4*)(xrow + 4);
    float4 g2 = *(const float4*)(xrow + 8);
    float4 g3 = *(const float4*)(xrow + 12);

    for (int kt = 0; kt < 8; ++kt) {
        u16x8 ha, hb;
        ha[0]=f2bf(g0.x); ha[1]=f2bf(g0.y); ha[2]=f2bf(g0.z); ha[3]=f2bf(g0.w);
        ha[4]=f2bf(g1.x); ha[5]=f2bf(g1.y); ha[6]=f2bf(g1.z); ha[7]=f2bf(g1.w);
        hb[0]=f2bf(g2.x); hb[1]=f2bf(g2.y); hb[2]=f2bf(g2.z); hb[3]=f2bf(g2.w);
        hb[4]=f2bf(g3.x); hb[5]=f2bf(g3.y); hb[6]=f2bf(g3.z); hb[7]=f2bf(g3.w);
        *(u16x8*)&As_w[r * 40 + h * 16]     = ha;
        *(u16x8*)&As_w[r * 40 + h * 16 + 8] = hb;

        if (kt < 7) {
            const float* xn = xrow + (kt + 1) * 32;
            g0 = *(const float4*)(xn + 0);
            g1 = *(const float4*)(xn + 4);
            g2 = *(const float4*)(xn + 8);
            g3 = *(const float4*)(xn + 12);
        }

        asm volatile("s_waitcnt lgkmcnt(0)" ::: "memory");

        bf16x8 af[2], bfr[8];
        #pragma unroll
        for (int rt = 0; rt < 2; ++rt)
            af[rt] = *(const bf16x8*)&As_w[(rt * 16 + m) * 40 + quad * 8];
        #pragma unroll
        for (int ct = 0; ct < 8; ++ct)
            bfr[ct] = *(const bf16x8*)&Bs[((kt * 4 + quad) * 128 + ct * 16 + m) * 8];
        #pragma unroll
        for (int rt = 0; rt < 2; ++rt)
            #pragma unroll
            for (int ct = 0; ct < 8; ++ct)
                acc[rt][ct] = __builtin_amdgcn_mfma_f32_16x16x32_bf16(
                    af[rt], bfr[ct], acc[rt][ct], 0, 0, 0);
    }

    const int b = m0 >> 12;
    const int jbase = (m0 & 4095) + w * 32;
    const int d0 = (nb & 1) * 128;

    if (nb < 2) {
        #pragma unroll
        for (int rt = 0; rt < 2; ++rt)
            #pragma unroll
            for (int ct = 0; ct < 8; ++ct) {
                int coll = ct * 16 + m;
                float bv = bias[d0 + coll];
                #pragma unroll
                for (int rr = 0; rr < 4; ++rr) {
                    int row = m0 + w * 32 + rt * 16 + quad * 4 + rr;
                    qb[(size_t)row * 256 + d0 + coll] = f2bf((acc[rt][ct][rr] + bv) * 0.0625f);
                }
            }
    } else if (nb < 4) {
        // K fragment-order w/ even-odd split: [b][jt][j&1][k8][qk*16 + (j>>1)][e]
        #pragma unroll
        for (int rt = 0; rt < 2; ++rt)
            #pragma unroll
            for (int ct = 0; ct < 8; ++ct) {
                int d = d0 + ct * 16 + m;
                float bv = bias[256 + d];
                int k8 = d >> 5, qk = (d >> 3) & 3, e = d & 7;
                #pragma unroll
                for (int rr = 0; rr < 4; ++rr) {
                    int j = jbase + rt * 16 + quad * 4 + rr;
                    int jt = j >> 5, jj = j & 31;
                    kb[((((size_t)(b * 128 + jt) * 2 + (jj & 1)) * 8 + k8) * 64 + qk * 16 + (jj >> 1)) * 8 + e]
                        = f2bf(acc[rt][ct][rr] + bv);
                }
            }
    } else {
        // V fragment-order: [b][jt][dt][qv*16+mv][e], e=j&7 -> u16x4 over rr
        #pragma unroll
        for (int rt = 0; rt < 2; ++rt)
            #pragma unroll
            for (int ct = 0; ct < 8; ++ct) {
                int d = d0 + ct * 16 + m;
                float bv = bias[512 + d];
                int dt = d >> 4, mv = d & 15;
                int j = jbase + rt * 16 + quad * 4;
                int jt = j >> 5, qv = (j >> 3) & 3, e0 = j & 7;
                u16x4 hv;
                #pragma unroll
                for (int rr = 0; rr < 4; ++rr) hv[rr] = f2bf(acc[rt][ct][rr] + bv);
                *(u16x4*)&vb[(((size_t)(b * 128 + jt) * 16 + dt) * 64 + qv * 16 + mv) * 8 + e0] = hv;
            }
    }
}

// ---------------------------------------------------------------------------
// Windowed flash-retention v5: t-parity wave specialization.
// 8 waves: waves 0-3 = rows 0..127 / EVEN key-tiles, waves 4-7 = same rows /
// ODD key-tiles. Pair of tiles staged per block-iter (64 KB, double-buffered).
// 2 waves/SIMD + 0.53 b128/MFMA. Partials combined in-block via retired LDS.
// grid 256 = 32 mt x 8 batches (batch = id%8 -> XCD-affine).
// ---------------------------------------------------------------------------
__global__ __launch_bounds__(512, 2) void attn_kernel(
        const u16* __restrict__ qb, const u16* __restrict__ kb,
        const u16* __restrict__ vb, float* __restrict__ out)
{
    __shared__ __align__(16) u16 KV[2][2][16384];  // [buf][tile-parity][K|V] 128 KB
    __shared__ __align__(16) u16 Ps[8 * 32 * 40];  // per-wave P (32 rows), 20 KB

    const int tid = threadIdx.x, lane = tid & 63, w = tid >> 6;   // w 0..7
    const int wp = w & 3, par = w >> 2;           // row-group, tile-parity
    const int l = blockIdx.x;
    const int b = l & 7;
    const int m0 = (l >> 3) * 128;                // l>>3 in [0,32)
    const int qrow0 = m0 + wp * 32;
    const int m = lane & 15, quad = lane >> 4;
    const size_t rowbase = (size_t)b * 4096;
    const size_t pbase = (size_t)b * 128;

    bf16x8 qf[2][8];
    #pragma unroll
    for (int rg = 0; rg < 2; ++rg)
        #pragma unroll
        for (int k8 = 0; k8 < 8; ++k8)
            qf[rg][k8] = *(const bf16x8*)(qb + (rowbase + qrow0 + rg * 16 + m) * 256 + k8 * 32 + quad * 8);

    f32x4 acc[2][16];
    #pragma unroll
    for (int rg = 0; rg < 2; ++rg)
        #pragma unroll
        for (int dt = 0; dt < 16; ++dt)
            acc[rg][dt] = f32x4{0.f, 0.f, 0.f, 0.f};

    int t0 = (m0 - 1024) >> 5; if (t0 < 0) t0 = 0;
    const int t1 = (m0 >> 5) + 3;
    const int nIter = (t1 - t0 + 2) >> 1;

    // initial stage: tiles (t0, t0+1) into buffer 0 (8 DMA lines/thread)
    {
        const u16* kpA = kb + (pbase + t0) * 8192;
        const u16* vpA = vb + (pbase + t0) * 8192;
        const u16* kpB = kpA + 8192;
        const u16* vpB = vpA + 8192;
        #pragma unroll
        for (int s = 0; s < 2; ++s) {
            int c = tid + 512 * s;                // 0..1023
            gl2lds16(kpA + (size_t)c * 8, &KV[0][0][c * 8]);
            gl2lds16(vpA + (size_t)c * 8, &KV[0][0][8192 + c * 8]);
            gl2lds16(kpB + (size_t)c * 8, &KV[0][1][c * 8]);
            gl2lds16(vpB + (size_t)c * 8, &KV[0][1][8192 + c * 8]);
        }
    }

    int p = 0;
    for (int it = 0; it < nIter; ++it) {
        __syncthreads();   // drains DMA into buf p; all waves done with buf p^1
        if (it + 1 < nIter) {
            const int ta = t0 + 2 * (it + 1);     // ta <= t1 guaranteed
            const bool haveB = (ta + 1 <= t1);    // block-uniform
            const u16* kpA = kb + (pbase + ta) * 8192;
            const u16* vpA = vb + (pbase + ta) * 8192;
            #pragma unroll
            for (int s = 0; s < 2; ++s) {
                int c = tid + 512 * s;
                gl2lds16(kpA + (size_t)c * 8, &KV[p ^ 1][0][c * 8]);
                gl2lds16(vpA + (size_t)c * 8, &KV[p ^ 1][0][8192 + c * 8]);
                if (haveB) {
                    gl2lds16(kpA + 8192 + (size_t)c * 8, &KV[p ^ 1][1][c * 8]);
                    gl2lds16(vpA + 8192 + (size_t)c * 8, &KV[p ^ 1][1][8192 + c * 8]);
                }
            }
        }

        const int t = t0 + 2 * it + par;
        const int j0 = t * 32;
        // wave-uniform: tile exists, not all-future, within decay window
        if (t <= t1 && j0 <= qrow0 + 31 && j0 + 1055 >= qrow0) {
            const u16* Kt = &KV[p][par][0];
            const u16* Vt = &KV[p][par][8192];

            // S = q.k^T : even-key half and odd-key half, b-frag reused x2
            f32x4 sA0{0.f,0.f,0.f,0.f}, sA1{0.f,0.f,0.f,0.f};
            f32x4 sB0{0.f,0.f,0.f,0.f}, sB1{0.f,0.f,0.f,0.f};
            #pragma unroll
            for (int k8 = 0; k8 < 8; ++k8) {
                bf16x8 bf0 = *(const bf16x8*)&Kt[(k8 * 64 + lane) * 8];
                sA0 = __builtin_amdgcn_mfma_f32_16x16x32_bf16(qf[0][k8], bf0, sA0, 0, 0, 0);
                sA1 = __builtin_amdgcn_mfma_f32_16x16x32_bf16(qf[1][k8], bf0, sA1, 0, 0, 0);
            }
            #pragma unroll
            for (int k8 = 0; k8 < 8; ++k8) {
                bf16x8 bf1 = *(const bf16x8*)&Kt[((8 + k8) * 64 + lane) * 8];
                sB0 = __builtin_amdgcn_mfma_f32_16x16x32_bf16(qf[0][k8], bf1, sB0, 0, 0, 0);
                sB1 = __builtin_amdgcn_mfma_f32_16x16x32_bf16(qf[1][k8], bf1, sB1, 0, 0, 0);
            }

            // decay-mask; sA = even keys (j0+2m), sB = odd keys (j0+2m+1);
            // pack the adjacent-key pair as one u32 LDS write
            #pragma unroll
            for (int rg = 0; rg < 2; ++rg) {
                f32x4 sh0 = rg ? sA1 : sA0;
                f32x4 sh1 = rg ? sB1 : sB0;
                #pragma unroll
                for (int rr = 0; rr < 4; ++rr) {
                    int i = qrow0 + rg * 16 + quad * 4 + rr;
                    int dd0 = i - (j0 + 2 * m);
                    int dd1 = dd0 - 1;
                    float w0 = (dd0 >= 0) ? __builtin_amdgcn_exp2f((float)dd0 * L2ALPHA) : 0.0f;
                    float w1 = (dd1 >= 0) ? __builtin_amdgcn_exp2f((float)dd1 * L2ALPHA) : 0.0f;
                    int rowb = (w * 32 + rg * 16 + quad * 4 + rr) * 40;
                    u32 pv = (u32)f2bf(sh0[rr] * w0) | ((u32)f2bf(sh1[rr] * w1) << 16);
                    *(u32*)&Ps[rowb + 2 * m] = pv;
                }
            }
            asm volatile("s_waitcnt lgkmcnt(0)" ::: "memory");  // wave-local P ready

            bf16x8 pa0 = *(const bf16x8*)&Ps[(w * 32 + m) * 40 + quad * 8];
            bf16x8 pa1 = *(const bf16x8*)&Ps[(w * 32 + 16 + m) * 40 + quad * 8];

            #pragma unroll
            for (int dt = 0; dt < 16; ++dt) {
                bf16x8 vf = *(const bf16x8*)&Vt[(dt * 64 + lane) * 8];
                acc[0][dt] = __builtin_amdgcn_mfma_f32_16x16x32_bf16(pa0, vf, acc[0][dt], 0, 0, 0);
                acc[1][dt] = __builtin_amdgcn_mfma_f32_16x16x32_bf16(pa1, vf, acc[1][dt], 0, 0, 0);
            }
        }
        p ^= 1;
    }

    // in-block combine: odd-parity partials through retired staging LDS
    __syncthreads();
    float* Comb = (float*)&KV[0][0][0];           // 32768 floats
    if (par == 1) {
        float* dst = Comb + (size_t)wp * 8192 + lane * 128;
        #pragma unroll
        for (int rg = 0; rg < 2; ++rg)
            #pragma unroll
            for (int dt = 0; dt < 16; ++dt)
                *(f32x4*)(dst + (rg * 16 + dt) * 4) = acc[rg][dt];
    }
    __syncthreads();
    if (par == 0) {
        const float* src = Comb + (size_t)wp * 8192 + lane * 128;
        #pragma unroll
        for (int rg = 0; rg < 2; ++rg)
            #pragma unroll
            for (int dt = 0; dt < 16; ++dt) {
                f32x4 o = acc[rg][dt] + *(const f32x4*)(src + (rg * 16 + dt) * 4);
                #pragma unroll
                for (int rr = 0; rr < 4; ++rr)
                    out[(rowbase + qrow0 + rg * 16 + quad * 4 + rr) * 256 + dt * 16 + m] = o[rr];
            }
    }
}

// ---------------------------------------------------------------------------
extern "C" void kernel_launch(void* const* d_in, const int* in_sizes, int n_in,
                              void* d_out, int out_size, void* d_ws, size_t ws_size,
                              hipStream_t stream) {
    (void)in_sizes; (void)n_in; (void)out_size; (void)ws_size;
    const float* x    = (const float*)d_in[0];
    const float* Wq   = (const float*)d_in[1];
    const float* bias = (const float*)d_in[2];
    float* outp = (float*)d_out;

    const size_t per = (size_t)8 * 4096 * 256;   // elems per q/k/v buffer (48 MB total)
    u16* qb = (u16*)d_ws;
    u16* kb = qb + per;
    u16* vb = kb + per;

    proj_kernel<<<1536, 256, 0, stream>>>(x, Wq, bias, qb, kb, vb);
    attn_kernel<<<256, 512, 0, stream>>>(qb, kb, vb, outp);
}